// Round 5
// baseline (92.341 us; speedup 1.0000x reference)
//
#include <hip/hip_runtime.h>
#include <math.h>

// Problem constants
#define BATCH 4
#define NPTS  2048
#define NT    256
#define ROWS_PT 4                 // rows per thread in pairwise
#define CPB     64                // columns per block in pairwise
#define COLCHUNKS (NPTS / CPB)    // 32
#define ROWHALVES 2               // 2048 / (NT*ROWS_PT)
#define ROWS_TOT  (BATCH * NPTS)  // 8192
#define RB_BLOCKS (ROWS_TOT / 128) // 64 rowreduce blocks

// Workspace layout (float units). All regions written unconditionally before
// being read -> no init needed despite 0xAA poison (counter zeroed by the
// pairwise dispatch, which precedes rowreduce in stream order).
//
// 3 matrices (transpose pairs deduplicated, bit-exact by commutativity of
// fadd and of the per-component products in the fma chain):
//   A = d(x_t1_hat, x_t1): row-min -> dist1, col-min -> dist2
//   B = d(y0, x_t0):       row-argmin -> keys,  col-min -> c1
//   C = d(y0, x_t1):       row-min -> rm3
#define CH_R      (COLCHUNKS * ROWS_TOT)           // 262144
#define OFF_PD1   0                                // [32][8192] f : A row-min partials
#define OFF_PRM3  CH_R                             // [32][8192] f : C row-min partials
#define OFF_PRM2  (2 * CH_R)                       // [32][8192] u64 : B packed (min,argmin)
#define OFF_PCA   (4 * CH_R)                       // [2][8192] f : A col-min partials
#define OFF_PCB   (OFF_PCA + 2 * ROWS_TOT)         // [2][8192] f : B col-min partials
#define OFF_BLK   (OFF_PCB + 2 * ROWS_TOT)         // [64][32] f per-block partials (128B stride)
#define OFF_CNT   (OFF_BLK + RB_BLOCKS * 32)       // u32 done-counter

#define INF_BITS 0x7f800000u

typedef unsigned long long ull;

__device__ __forceinline__ float sqnorm3(float x, float y, float z) {
    // mimic jnp.sum(a*a, -1): squares then left-assoc add chain, no fma contraction
    return __fadd_rn(__fadd_rn(__fmul_rn(x, x), __fmul_rn(y, y)), __fmul_rn(z, z));
}

// point sources
#define SRC_T0  0
#define SRC_T1  1
#define SRC_T1H 2
#define SRC_Y0  3

// col=true: returns (-2x, -2y, -2z, sqnorm(x,y,z)); scaling by -2 is exact,
// so each fma partial is bit-exactly -2x the reference partial and
// fadd(u, dot') == fsub(u, fmul(2, dot)) for every input.
__device__ __forceinline__ float4 make_point(int src, bool col, int b, int i,
    const float* __restrict__ x, const float* __restrict__ m_hat,
    const float* __restrict__ y_hat0)
{
    float px, py, pz;
    if (src == SRC_Y0) {
        const float* p = y_hat0 + ((size_t)b * NPTS + i) * 3;
        px = p[0]; py = p[1]; pz = p[2];
    } else if (src == SRC_T1) {
        const float* p = x + ((size_t)(b * 2 + 1) * NPTS + i) * 3;
        px = p[0]; py = p[1]; pz = p[2];
    } else {
        const float* p = x + ((size_t)(b * 2 + 0) * NPTS + i) * 3;
        px = p[0]; py = p[1]; pz = p[2];
        if (src == SRC_T1H) {           // x_t0 + m_hat (same op order as before)
            const float* mh = m_hat + ((size_t)b * NPTS + i) * 3;
            px += mh[0]; py += mh[1]; pz += mh[2];
        }
    }
    float w = sqnorm3(px, py, pz);
    if (col) { px *= -2.0f; py *= -2.0f; pz *= -2.0f; }
    return make_float4(px, py, pz, w);
}

__device__ __forceinline__ ull shfl_xor_u64(ull v, int m) {
    int lo = __shfl_xor((int)(v & 0xFFFFFFFFull), m);
    int hi = __shfl_xor((int)(v >> 32), m);
    return ((ull)(unsigned)hi << 32) | (unsigned)lo;
}

// 64-lane min butterfly; fmin is exact & order-insensitive (no NaNs here).
__device__ __forceinline__ float wave_min(float v) {
    #pragma unroll
    for (int m = 1; m < 64; m <<= 1) v = fminf(v, __shfl_xor(v, m));
    return v;
}

__device__ __forceinline__ float dist_sq(const float4& a, const float4& q) {
    float s = a.x * q.x + a.y * q.y + a.z * q.z;   // fma chain; q pre-scaled by -2
    float u = __fadd_rn(a.w, q.w);
    return fmaxf(__fadd_rn(u, s), 0.0f);
}

// ---------------------------------------------------------------- pairwise
// grid: x = rowHalf(2)*colChunk(32) -> 64, y = batch(4), z = matrix(3)
// 768 blocks = 3 blocks/CU. Inline prep; deterministic partial-slot writes.
__global__ __launch_bounds__(NT) void pairwise_kernel(
    const float* __restrict__ x, const float* __restrict__ m_hat,
    const float* __restrict__ y_hat0, float* __restrict__ ws)
{
    __shared__ float4 tile[CPB];
    __shared__ float  cw[4][CPB];

    int tid = threadIdx.x;
    int rowHalf  = blockIdx.x >> 5;
    int colChunk = blockIdx.x & 31;
    int b   = blockIdx.y;
    int mat = blockIdx.z;

    // zero the done-counter for the next dispatch (kernel-boundary coherence)
    if (blockIdx.x == 0 && b == 0 && mat == 0 && tid == 0)
        ((unsigned*)ws)[OFF_CNT] = 0u;

    int rsrc, csrc;
    switch (mat) {
        case 0:  rsrc = SRC_T1H; csrc = SRC_T1; break;   // A
        case 1:  rsrc = SRC_Y0;  csrc = SRC_T0; break;   // B (argmin + colmin)
        default: rsrc = SRC_Y0;  csrc = SRC_T1; break;   // C (rowmin only)
    }

    int colBase = colChunk * CPB;
    if (tid < CPB) tile[tid] = make_point(csrc, true, b, colBase + tid, x, m_hat, y_hat0);

    int r0 = rowHalf * (NT * ROWS_PT) + tid;
    float4 a[ROWS_PT];
    #pragma unroll
    for (int k = 0; k < ROWS_PT; ++k)
        a[k] = make_point(rsrc, false, b, r0 + k * NT, x, m_hat, y_hat0);

    __syncthreads();

    int wv = tid >> 6;
    size_t rowSlot = (size_t)colChunk * ROWS_TOT + b * NPTS + r0;   // + k*NT
    size_t colSlot = (size_t)rowHalf * ROWS_TOT + b * NPTS + colBase; // + t

    if (mat == 0) {                       // ---- A: row-min + col-min
        float best[ROWS_PT];
        #pragma unroll
        for (int k = 0; k < ROWS_PT; ++k) best[k] = __uint_as_float(INF_BITS);
        for (int c = 0; c < CPB; ++c) {
            float4 q = tile[c];
            float d0 = dist_sq(a[0], q), d1 = dist_sq(a[1], q);
            float d2 = dist_sq(a[2], q), d3 = dist_sq(a[3], q);
            best[0] = fminf(best[0], d0); best[1] = fminf(best[1], d1);
            best[2] = fminf(best[2], d2); best[3] = fminf(best[3], d3);
            float colv = wave_min(fminf(fminf(d0, d1), fminf(d2, d3)));
            if ((tid & 63) == 0) cw[wv][c] = colv;
        }
        #pragma unroll
        for (int k = 0; k < ROWS_PT; ++k)
            ws[OFF_PD1 + rowSlot + k * NT] = best[k];
        __syncthreads();
        if (tid < CPB)
            ws[OFF_PCA + colSlot + tid] =
                fminf(fminf(cw[0][tid], cw[1][tid]), fminf(cw[2][tid], cw[3][tid]));
    } else if (mat == 1) {                // ---- B: row-argmin + col-min
        float best[ROWS_PT];
        int bestIdx[ROWS_PT];
        #pragma unroll
        for (int k = 0; k < ROWS_PT; ++k) { best[k] = __uint_as_float(INF_BITS); bestIdx[k] = 0; }
        for (int c = 0; c < CPB; ++c) {
            float4 q = tile[c];
            float d0 = dist_sq(a[0], q), d1 = dist_sq(a[1], q);
            float d2 = dist_sq(a[2], q), d3 = dist_sq(a[3], q);
            if (d0 < best[0]) { best[0] = d0; bestIdx[0] = c; }   // first-occurrence
            if (d1 < best[1]) { best[1] = d1; bestIdx[1] = c; }
            if (d2 < best[2]) { best[2] = d2; bestIdx[2] = c; }
            if (d3 < best[3]) { best[3] = d3; bestIdx[3] = c; }
            float colv = wave_min(fminf(fminf(d0, d1), fminf(d2, d3)));
            if ((tid & 63) == 0) cw[wv][c] = colv;
        }
        ull* prm2 = (ull*)(ws + OFF_PRM2);
        #pragma unroll
        for (int k = 0; k < ROWS_PT; ++k) {
            ull key = ((ull)__float_as_uint(best[k]) << 32) |
                      (unsigned)(colBase + bestIdx[k]);
            prm2[rowSlot + k * NT] = key;
        }
        __syncthreads();
        if (tid < CPB)
            ws[OFF_PCB + colSlot + tid] =
                fminf(fminf(cw[0][tid], cw[1][tid]), fminf(cw[2][tid], cw[3][tid]));
    } else {                              // ---- C: row-min only
        float best[ROWS_PT];
        #pragma unroll
        for (int k = 0; k < ROWS_PT; ++k) best[k] = __uint_as_float(INF_BITS);
        for (int c = 0; c < CPB; ++c) {
            float4 q = tile[c];
            best[0] = fminf(best[0], dist_sq(a[0], q));
            best[1] = fminf(best[1], dist_sq(a[1], q));
            best[2] = fminf(best[2], dist_sq(a[2], q));
            best[3] = fminf(best[3], dist_sq(a[3], q));
        }
        #pragma unroll
        for (int k = 0; k < ROWS_PT; ++k)
            ws[OFF_PRM3 + rowSlot + k * NT] = best[k];
    }
}

// ---------------------------------------------------------------- row reduce + finalize + combine
// grid: 64 blocks x 256. 2 threads per row (16 chunks each), shfl_xor combine,
// per-row finalize math, per-block partial -> OFF_BLK. Last block combines.
__global__ __launch_bounds__(NT) void rowreduce_kernel(
    const float* __restrict__ m_hat, const float* __restrict__ y_hat0,
    const float* __restrict__ y_hat1, float* __restrict__ ws, float* __restrict__ out)
{
    int tid  = threadIdx.x;
    int row  = blockIdx.x * 128 + (tid >> 1);   // [0, 8192)
    int half = tid & 1;
    int b    = row >> 11;

    const ull* prm2 = (const ull*)(ws + OFF_PRM2);

    float d1m = __uint_as_float(INF_BITS), r3m = d1m;
    ull k2 = ~0ull;
    #pragma unroll
    for (int c = 0; c < 16; ++c) {
        int idx = (half * 16 + c) * ROWS_TOT + row;
        d1m = fminf(d1m, ws[OFF_PD1 + idx]);
        r3m = fminf(r3m, ws[OFF_PRM3 + idx]);
        ull kk = prm2[idx];
        k2 = (kk < k2) ? kk : k2;
    }
    // col-combined values (2 partials each; fmin exact in any order)
    float d2m = fminf(ws[OFF_PCA + row], ws[OFF_PCA + ROWS_TOT + row]);
    float c1m = fminf(ws[OFF_PCB + row], ws[OFF_PCB + ROWS_TOT + row]);

    d1m = fminf(d1m, __shfl_xor(d1m, 1));
    r3m = fminf(r3m, __shfl_xor(r3m, 1));
    { ull o = shfl_xor_u64(k2, 1); k2 = (o < k2) ? o : k2; }

    float d2sq = __uint_as_float((unsigned)(k2 >> 32));
    unsigned idxm = (unsigned)(k2 & 0xFFFFFFFFull);
    float md   = (sqrtf(d2sq) < 0.05f) ? 1.0f : 0.0f;
    float dcat = fminf(d2sq, r3m);
    float mneg = (sqrtf(dcat) > 0.2f) ? 1.0f : 0.0f;

    const float* p0 = y_hat0 + (size_t)row * 3;
    const float* p1 = y_hat1 + (size_t)row * 3;
    const float* nm = m_hat + ((size_t)b * NPTS + idxm) * 3;

    float dyn = 0.f, stat = 0.f;
    #pragma unroll
    for (int k = 0; k < 3; ++k) {
        float diff = p1[k] - p0[k];
        float e = md * (diff - nm[k]);      // masks are 0/1 -> exact
        dyn += e * e;
        float s = mneg * diff;
        stat += s * s;
    }
    float cs = (c1m < 0.1f) ? c1m : 0.f;
    float cn = (c1m < 0.1f) ? 1.f  : 0.f;
    float s1 = d1m, s2 = d2m;
    if (half) { s1 = s2 = cs = cn = dyn = stat = 0.f; }   // avoid double count

    #pragma unroll
    for (int off = 32; off > 0; off >>= 1) {
        s1  += __shfl_down(s1,  off);
        s2  += __shfl_down(s2,  off);
        cs  += __shfl_down(cs,  off);
        cn  += __shfl_down(cn,  off);
        dyn += __shfl_down(dyn, off);
        stat+= __shfl_down(stat,off);
    }
    __shared__ float sm[4][6];
    int wv = tid >> 6, ln = tid & 63;
    if (ln == 0) {
        sm[wv][0] = s1; sm[wv][1] = s2; sm[wv][2] = cs;
        sm[wv][3] = cn; sm[wv][4] = dyn; sm[wv][5] = stat;
    }
    __syncthreads();

    __shared__ int sLast;
    if (tid == 0) {
        #pragma unroll
        for (int j = 0; j < 6; ++j)
            ws[OFF_BLK + blockIdx.x * 32 + j] = sm[0][j] + sm[1][j] + sm[2][j] + sm[3][j];
        __threadfence();   // device-scope release of our partial
        unsigned old = atomicAdd((unsigned*)ws + OFF_CNT, 1u);
        sLast = (old == RB_BLOCKS - 1) ? 1 : 0;
    }
    __syncthreads();
    if (!sLast) return;

    // ---- last block: 64 -> 3 combine (identical tree to prior rounds)
    __threadfence();       // acquire
    int lane = tid;
    if (lane < 64) {
        float v[6];
        #pragma unroll
        for (int j = 0; j < 6; ++j) v[j] = ws[OFF_BLK + lane * 32 + j];
        #pragma unroll
        for (int off = 8; off > 0; off >>= 1) {
            #pragma unroll
            for (int j = 0; j < 6; ++j) {
                float t = __shfl_down(v[j], off);
                if (((lane & 15) + off) < 16) v[j] += t;
            }
        }
        __shared__ float bs[4][6];
        if ((lane & 15) == 0) {
            #pragma unroll
            for (int j = 0; j < 6; ++j) bs[lane >> 4][j] = v[j];
        }
        __builtin_amdgcn_s_waitcnt(0);  // single-wave LDS visibility (validated R4)
        if (lane == 0) {
            float dyn = 0.f, stat = 0.f, cs = 0.f, cn = 0.f;
            for (int bb = 0; bb < 4; ++bb) {
                float lc = bs[bb][0] / (float)NPTS + bs[bb][1] / (float)NPTS;
                float maskc = (lc < 0.1f) ? 1.0f : 0.0f;
                dyn  += maskc * bs[bb][4];
                stat += bs[bb][5];
                cs   += bs[bb][2];
                cn   += bs[bb][3];
            }
            const float denom = (float)(BATCH * NPTS * 3);   // 24576
            out[0] = dyn / denom;
            out[1] = stat / denom;
            out[2] = cs / fmaxf(cn, 1.0f);
        }
    }
}

extern "C" void kernel_launch(void* const* d_in, const int* in_sizes, int n_in,
                              void* d_out, int out_size, void* d_ws, size_t ws_size,
                              hipStream_t stream)
{
    const float* x      = (const float*)d_in[0];
    const float* m_hat  = (const float*)d_in[1];
    const float* y_hat0 = (const float*)d_in[2];
    const float* y_hat1 = (const float*)d_in[3];
    float* ws  = (float*)d_ws;
    float* out = (float*)d_out;

    pairwise_kernel<<<dim3(ROWHALVES * COLCHUNKS, BATCH, 3), dim3(NT), 0, stream>>>(
        x, m_hat, y_hat0, ws);
    rowreduce_kernel<<<dim3(RB_BLOCKS), dim3(NT), 0, stream>>>(
        m_hat, y_hat0, y_hat1, ws, out);
}

// Round 7
// 85.599 us; speedup vs baseline: 1.0788x; 1.0788x over previous
//
#include <hip/hip_runtime.h>
#include <math.h>

// Problem constants
#define BATCH 4
#define NPTS  2048
#define NT    256
#define ROWS_PT 4                 // rows per thread in pairwise
#define CPB     64                // columns per block in pairwise
#define COLCHUNKS (NPTS / CPB)    // 32
#define ROWHALVES 2               // 2048 / (NT*ROWS_PT)
#define ROWS_TOT  (BATCH * NPTS)  // 8192
#define RB_BLOCKS (ROWS_TOT / 128) // 64 rowreduce blocks

// Workspace layout (float units). All regions written unconditionally before
// being read -> no init needed despite 0xAA poison. No atomics, no fences.
#define OFF_PD1   0                                // [32][8192] f : chunk-partial min, dist1 (unclamped)
#define OFF_PD2   (COLCHUNKS * ROWS_TOT)           // dist2 (unclamped)
#define OFF_PC1   (2 * COLCHUNKS * ROWS_TOT)       // c1    (unclamped)
#define OFF_PRM3  (3 * COLCHUNKS * ROWS_TOT)       // rowmin y0->x_t1 (unclamped)
#define OFF_PRM2  (4 * COLCHUNKS * ROWS_TOT)       // [32][8192] u64 packed (clamped min, argmin)
#define OFF_BLK   (6 * COLCHUNKS * ROWS_TOT)       // [64][8] f per-block partial sums
#define INF_BITS 0x7f800000u

typedef unsigned long long ull;

__device__ __forceinline__ float sqnorm3(float x, float y, float z) {
    // mimic jnp.sum(a*a, -1): squares then left-assoc add chain, no fma contraction
    return __fadd_rn(__fadd_rn(__fmul_rn(x, x), __fmul_rn(y, y)), __fmul_rn(z, z));
}

// point sources
#define SRC_T0  0
#define SRC_T1  1
#define SRC_T1H 2
#define SRC_Y0  3

// col=true: returns (-2x, -2y, -2z, sqnorm(x,y,z)); scaling by -2 is exact,
// so fadd(u, dot') == fsub(u, fmul(2, dot)) bit-exactly (validated R4/R5).
__device__ __forceinline__ float4 make_point(int src, bool col, int b, int i,
    const float* __restrict__ x, const float* __restrict__ m_hat,
    const float* __restrict__ y_hat0)
{
    float px, py, pz;
    if (src == SRC_Y0) {
        const float* p = y_hat0 + ((size_t)b * NPTS + i) * 3;
        px = p[0]; py = p[1]; pz = p[2];
    } else if (src == SRC_T1) {
        const float* p = x + ((size_t)(b * 2 + 1) * NPTS + i) * 3;
        px = p[0]; py = p[1]; pz = p[2];
    } else {
        const float* p = x + ((size_t)(b * 2 + 0) * NPTS + i) * 3;
        px = p[0]; py = p[1]; pz = p[2];
        if (src == SRC_T1H) {           // x_t0 + m_hat (same op order as before)
            const float* mh = m_hat + ((size_t)b * NPTS + i) * 3;
            px += mh[0]; py += mh[1]; pz += mh[2];
        }
    }
    float w = sqnorm3(px, py, pz);
    if (col) { px *= -2.0f; py *= -2.0f; pz *= -2.0f; }
    return make_float4(px, py, pz, w);
}

__device__ __forceinline__ ull shfl_xor_u64(ull v, int m) {
    int lo = __shfl_xor((int)(v & 0xFFFFFFFFull), m);
    int hi = __shfl_xor((int)(v >> 32), m);
    return ((ull)(unsigned)hi << 32) | (unsigned)lo;
}

// unclamped squared distance: 6 VALU (mul, fma, fma, fadd, fadd).
// Clamp max(.,0) is monotone -> hoisted outside min-reductions (bit-exact):
//   min_c max(d_c,0) == max(min_c d_c, 0)
__device__ __forceinline__ float dist_sq_raw(const float4& a, const float4& q) {
    float s = a.x * q.x + a.y * q.y + a.z * q.z;   // fma chain; q pre-scaled by -2
    float u = __fadd_rn(a.w, q.w);
    return __fadd_rn(u, s);
}

// ---------------------------------------------------------------- pairwise
// grid: x = rowHalf(2)*colChunk(32) -> 64, y = batch(4), z = problem(5)
// 1280 blocks = 5 blocks/CU. Inline prep; deterministic partial-slot writes.
// R5 lesson: NO cross-lane reduction in the inner loop (pure ILP body).
__global__ __launch_bounds__(NT) void pairwise_kernel(
    const float* __restrict__ x, const float* __restrict__ m_hat,
    const float* __restrict__ y_hat0, float* __restrict__ ws)
{
    __shared__ float4 tile[CPB];

    int tid = threadIdx.x;
    int rowHalf  = blockIdx.x >> 5;
    int colChunk = blockIdx.x & 31;
    int b    = blockIdx.y;
    int prob = blockIdx.z;

    int rsrc, csrc, outOff;
    switch (prob) {
        case 0:  rsrc = SRC_T1H; csrc = SRC_T1;  outOff = OFF_PD1;  break;
        case 1:  rsrc = SRC_T1;  csrc = SRC_T1H; outOff = OFF_PD2;  break;
        case 2:  rsrc = SRC_Y0;  csrc = SRC_T0;  outOff = -1;       break; // argmin path
        case 3:  rsrc = SRC_Y0;  csrc = SRC_T1;  outOff = OFF_PRM3; break;
        default: rsrc = SRC_T0;  csrc = SRC_Y0;  outOff = OFF_PC1;  break;
    }

    int colBase = colChunk * CPB;
    if (tid < CPB) tile[tid] = make_point(csrc, true, b, colBase + tid, x, m_hat, y_hat0);

    int r0 = rowHalf * (NT * ROWS_PT) + tid;
    float4 a[ROWS_PT];
    #pragma unroll
    for (int k = 0; k < ROWS_PT; ++k)
        a[k] = make_point(rsrc, false, b, r0 + k * NT, x, m_hat, y_hat0);

    __syncthreads();

    if (prob == 2) {
        // argmin needs per-c clamped values (clamp can reorder <=0 ties),
        // so keep fmax inside the loop here only.
        float best[ROWS_PT];
        int bestIdx[ROWS_PT];
        #pragma unroll
        for (int k = 0; k < ROWS_PT; ++k) { best[k] = __uint_as_float(INF_BITS); bestIdx[k] = 0; }
        for (int c = 0; c < CPB; ++c) {
            float4 q = tile[c];
            #pragma unroll
            for (int k = 0; k < ROWS_PT; ++k) {
                float d = fmaxf(dist_sq_raw(a[k], q), 0.0f);
                if (d < best[k]) { best[k] = d; bestIdx[k] = c; }   // first-occurrence
            }
        }
        ull* prm2 = (ull*)(ws + OFF_PRM2);
        #pragma unroll
        for (int k = 0; k < ROWS_PT; ++k) {
            ull key = ((ull)__float_as_uint(best[k]) << 32) |
                      (unsigned)(colBase + bestIdx[k]);
            prm2[(size_t)colChunk * ROWS_TOT + b * NPTS + r0 + k * NT] = key;
        }
    } else {
        float best[ROWS_PT];
        #pragma unroll
        for (int k = 0; k < ROWS_PT; ++k) best[k] = __uint_as_float(INF_BITS);
        for (int c = 0; c < CPB; ++c) {
            float4 q = tile[c];
            #pragma unroll
            for (int k = 0; k < ROWS_PT; ++k)
                best[k] = fminf(best[k], dist_sq_raw(a[k], q));     // clamp hoisted
        }
        #pragma unroll
        for (int k = 0; k < ROWS_PT; ++k)
            ws[outOff + (size_t)colChunk * ROWS_TOT + b * NPTS + r0 + k * NT] = best[k];
    }
}

// ---------------------------------------------------------------- row reduce + finalize
// grid: 64 blocks x 256. 2 threads per row (16 chunks each), shfl_xor combine,
// hoisted clamp applied once per row, per-block partial sums -> OFF_BLK.
__global__ __launch_bounds__(NT) void rowreduce_kernel(
    const float* __restrict__ m_hat, const float* __restrict__ y_hat0,
    const float* __restrict__ y_hat1, float* __restrict__ ws)
{
    int tid  = threadIdx.x;
    int row  = blockIdx.x * 128 + (tid >> 1);   // [0, 8192)
    int half = tid & 1;
    int b    = row >> 11;

    const ull* prm2 = (const ull*)(ws + OFF_PRM2);

    float d1m = __uint_as_float(INF_BITS), d2m = d1m, c1m = d1m, r3m = d1m;
    ull k2 = ~0ull;
    #pragma unroll
    for (int c = 0; c < 16; ++c) {
        int idx = (half * 16 + c) * ROWS_TOT + row;
        d1m = fminf(d1m, ws[OFF_PD1 + idx]);
        d2m = fminf(d2m, ws[OFF_PD2 + idx]);
        c1m = fminf(c1m, ws[OFF_PC1 + idx]);
        r3m = fminf(r3m, ws[OFF_PRM3 + idx]);
        ull kk = prm2[idx];
        k2 = (kk < k2) ? kk : k2;
    }
    d1m = fminf(d1m, __shfl_xor(d1m, 1));
    d2m = fminf(d2m, __shfl_xor(d2m, 1));
    c1m = fminf(c1m, __shfl_xor(c1m, 1));
    r3m = fminf(r3m, __shfl_xor(r3m, 1));
    { ull o = shfl_xor_u64(k2, 1); k2 = (o < k2) ? o : k2; }

    // hoisted clamps (bit-exact: max monotone commutes with min)
    d1m = fmaxf(d1m, 0.0f);
    d2m = fmaxf(d2m, 0.0f);
    c1m = fmaxf(c1m, 0.0f);
    r3m = fmaxf(r3m, 0.0f);

    float d2sq = __uint_as_float((unsigned)(k2 >> 32));
    unsigned idxm = (unsigned)(k2 & 0xFFFFFFFFull);
    float md   = (sqrtf(d2sq) < 0.05f) ? 1.0f : 0.0f;
    float dcat = fminf(d2sq, r3m);
    float mneg = (sqrtf(dcat) > 0.2f) ? 1.0f : 0.0f;

    const float* p0 = y_hat0 + (size_t)row * 3;
    const float* p1 = y_hat1 + (size_t)row * 3;
    const float* nm = m_hat + ((size_t)b * NPTS + idxm) * 3;

    float dyn = 0.f, stat = 0.f;
    #pragma unroll
    for (int k = 0; k < 3; ++k) {
        float diff = p1[k] - p0[k];
        float e = md * (diff - nm[k]);      // masks are 0/1 -> exact
        dyn += e * e;
        float s = mneg * diff;
        stat += s * s;
    }
    float cs = (c1m < 0.1f) ? c1m : 0.f;
    float cn = (c1m < 0.1f) ? 1.f  : 0.f;
    float s1 = d1m, s2 = d2m;
    if (half) { s1 = s2 = cs = cn = dyn = stat = 0.f; }   // avoid double count

    #pragma unroll
    for (int off = 32; off > 0; off >>= 1) {
        s1  += __shfl_down(s1,  off);
        s2  += __shfl_down(s2,  off);
        cs  += __shfl_down(cs,  off);
        cn  += __shfl_down(cn,  off);
        dyn += __shfl_down(dyn, off);
        stat+= __shfl_down(stat,off);
    }
    __shared__ float sm[4][6];
    int wv = tid >> 6, ln = tid & 63;
    if (ln == 0) {
        sm[wv][0] = s1; sm[wv][1] = s2; sm[wv][2] = cs;
        sm[wv][3] = cn; sm[wv][4] = dyn; sm[wv][5] = stat;
    }
    __syncthreads();
    if (tid == 0) {
        #pragma unroll
        for (int j = 0; j < 6; ++j)
            ws[OFF_BLK + blockIdx.x * 8 + j] = sm[0][j] + sm[1][j] + sm[2][j] + sm[3][j];
    }
}

// ---------------------------------------------------------------- final combine
// 1 block x 64, identical tree to R2/R3 (validated bit-exact).
__global__ void final_kernel(const float* __restrict__ ws, float* __restrict__ out)
{
    int lane = threadIdx.x;    // 0..63
    float v[6];
    #pragma unroll
    for (int j = 0; j < 6; ++j) v[j] = ws[OFF_BLK + lane * 8 + j];
    #pragma unroll
    for (int off = 8; off > 0; off >>= 1) {
        #pragma unroll
        for (int j = 0; j < 6; ++j) {
            float t = __shfl_down(v[j], off);
            if (((lane & 15) + off) < 16) v[j] += t;
        }
    }
    __shared__ float bs[4][6];
    if ((lane & 15) == 0) {
        #pragma unroll
        for (int j = 0; j < 6; ++j) bs[lane >> 4][j] = v[j];
    }
    __syncthreads();
    if (lane == 0) {
        float dyn = 0.f, stat = 0.f, cs = 0.f, cn = 0.f;
        for (int b = 0; b < 4; ++b) {
            float lc = bs[b][0] / (float)NPTS + bs[b][1] / (float)NPTS;
            float maskc = (lc < 0.1f) ? 1.0f : 0.0f;
            dyn  += maskc * bs[b][4];
            stat += bs[b][5];
            cs   += bs[b][2];
            cn   += bs[b][3];
        }
        const float denom = (float)(BATCH * NPTS * 3);   // 24576
        out[0] = dyn / denom;
        out[1] = stat / denom;
        out[2] = cs / fmaxf(cn, 1.0f);
    }
}

extern "C" void kernel_launch(void* const* d_in, const int* in_sizes, int n_in,
                              void* d_out, int out_size, void* d_ws, size_t ws_size,
                              hipStream_t stream)
{
    const float* x      = (const float*)d_in[0];
    const float* m_hat  = (const float*)d_in[1];
    const float* y_hat0 = (const float*)d_in[2];
    const float* y_hat1 = (const float*)d_in[3];
    float* ws  = (float*)d_ws;
    float* out = (float*)d_out;

    pairwise_kernel<<<dim3(ROWHALVES * COLCHUNKS, BATCH, 5), dim3(NT), 0, stream>>>(
        x, m_hat, y_hat0, ws);
    rowreduce_kernel<<<dim3(RB_BLOCKS), dim3(NT), 0, stream>>>(
        m_hat, y_hat0, y_hat1, ws);
    final_kernel<<<dim3(1), dim3(64), 0, stream>>>(ws, out);
}